// Round 11
// baseline (3753.669 us; speedup 1.0000x reference)
//
#include <hip/hip_runtime.h>
#include <stdint.h>

// P_TNCN: seq=512, batch=128, states=512, out=256, inv_tau=0.5,
// alpha=0.01, beta=0.5.  float32 I/O.
//
// Per step (per batch row b, independent across b):
//   h_prior = 0.5*h + 0.5*(tanh(h) @ w_r^T + b_r)          [w_i term == 0]
//   x_pred  = tanh(h_prior) @ w_o^T + b_o
//   error   = x_pred - x_t                                   (output)
//   h_post  = h_prior - 0.01*sign(h_prior) - 0.5*(error @ w_f^T)
//
// R13: REVERT R12 (f8->i8 w_f byte-cut regressed 2775->3195us, stall grew
// unexplained; rigor rule: unexplained change = reverted).  Base = R11
// (i8 w_r/w_o via sdot4, f16 w_f, 584 KB/step L2 stream, NST=7 LDS-staged A
// rows, 128 blk x 512 thr) + two zero-numeric-risk overhead cuts:
//  1. Phase B by 256 threads over the FULL k-range (same bytes): error
//     computed directly -> part[] reduction barrier + LDS round-trip gone
//     (4 barriers/step -> 3).
//  2. Even/odd accumulator-chain splits in all phases (int adds exact;
//     f16 phase-C reorder ~1e-7).
// Workspace: 640 KB + 8 B.

#define SEQ   512
#define BATCH 128
#define SD    512
#define OD    256
#define NST   7     // A rows staged in LDS (7*512*16B = 57344 B)

typedef _Float16 h2_t __attribute__((ext_vector_type(2)));

#if __has_builtin(__builtin_amdgcn_fdot2)
#define HAS_FDOT2 1
#else
#define HAS_FDOT2 0
#endif
#if __has_builtin(__builtin_amdgcn_sdot4)
#define HAS_SDOT4 1
#else
#define HAS_SDOT4 0
#endif

__device__ __forceinline__ float tanh_fast(float x) {
    float e = __expf(2.0f * x);
    return 1.0f - 2.0f / (e + 1.0f);
}

__device__ __forceinline__ uint32_t pack_h2(float a, float b) {
    h2_t v;
    v.x = (_Float16)a;
    v.y = (_Float16)b;
    return __builtin_bit_cast(uint32_t, v);
}

__device__ __forceinline__ float dot2acc(uint32_t w, uint32_t a, float acc) {
#if HAS_FDOT2
    return __builtin_amdgcn_fdot2(__builtin_bit_cast(h2_t, a),
                                  __builtin_bit_cast(h2_t, w), acc, false);
#else
    h2_t av = __builtin_bit_cast(h2_t, a);
    h2_t wv = __builtin_bit_cast(h2_t, w);
    acc += (float)av.x * (float)wv.x;
    acc += (float)av.y * (float)wv.y;
    return acc;
#endif
}

// f16 path (phase C): uint4 = 8 f16 weights vs 8 f16 acts.
__device__ __forceinline__ float dot8(uint4 w, uint4 a, float acc) {
    acc = dot2acc(w.x, a.x, acc);
    acc = dot2acc(w.y, a.y, acc);
    acc = dot2acc(w.z, a.z, acc);
    acc = dot2acc(w.w, a.w, acc);
    return acc;
}

// i8 path: 4 signed-i8 MACs per instruction, i32 accumulate.
__device__ __forceinline__ int dot4i(uint32_t w, uint32_t a, int acc) {
#if HAS_SDOT4
    return __builtin_amdgcn_sdot4((int)w, (int)a, acc, false);
#else
    #pragma unroll
    for (int i = 0; i < 4; ++i)
        acc += (int)(signed char)((w >> (8 * i)) & 0xffu)
             * (int)(signed char)((a >> (8 * i)) & 0xffu);
    return acc;
#endif
}
// uint4 = 16 i8 weights vs 16 i8 acts.
__device__ __forceinline__ int dot16i(uint4 w, uint4 a, int acc) {
    acc = dot4i(w.x, a.x, acc);
    acc = dot4i(w.y, a.y, acc);
    acc = dot4i(w.z, a.z, acc);
    acc = dot4i(w.w, a.w, acc);
    return acc;
}

// ---------------------------------------------------------------------------
// Workspace layout (uint4 units):
//   A8i [32][512] : i8 w_r, A8i[k16][s] bytes = w_r[s][16k16..16k16+15] (256 KB)
//   O8i [32][256] : i8 w_o, O8i[k16][o] likewise                        (128 KB)
//   F4  [32][512] : f16 w_f, F4[o8][s] = w_f[s][8o8..8o8+7]             (256 KB)
//   scales: 2 floats at uint4-offset 40960: max|w_r|, max|w_o|.
// ---------------------------------------------------------------------------

__global__ void compute_scales(const float* __restrict__ w_r,
                               const float* __restrict__ w_o,
                               float* __restrict__ sc)
{
    __shared__ float red[1024];
    const float* src = (blockIdx.x == 0) ? w_r : w_o;
    const int n = (blockIdx.x == 0) ? (512 * 512) : (256 * 512);
    float m = 0.0f;
    for (int i = threadIdx.x; i < n; i += 1024) m = fmaxf(m, fabsf(src[i]));
    red[threadIdx.x] = m;
    __syncthreads();
    for (int off = 512; off > 0; off >>= 1) {
        if (threadIdx.x < off)
            red[threadIdx.x] = fmaxf(red[threadIdx.x], red[threadIdx.x + off]);
        __syncthreads();
    }
    if (threadIdx.x == 0) sc[blockIdx.x] = fmaxf(red[0], 1e-20f);
}

__global__ void pack_weights(const float* __restrict__ w_o,
                             const float* __restrict__ w_r,
                             const float* __restrict__ w_f,
                             uint4* __restrict__ ws)
{
    const int nA = 32 * 512;   // 16384 uint4
    const int nO = 32 * 256;   //  8192
    const int nF = 32 * 512;   // 16384
    const float* sc = (const float*)(ws + nA + nO + nF);
    int i = blockIdx.x * 256 + threadIdx.x;
    if (i < nA + nO) {
        const float* p;
        float qs;
        if (i < nA) {
            int k16 = i >> 9, s = i & 511;
            p  = &w_r[s * 512 + 16 * k16];
            qs = 127.0f / sc[0];
        } else {
            int j = i - nA;
            int k16 = j >> 8, o = j & 255;
            p  = &w_o[o * 512 + 16 * k16];
            qs = 127.0f / sc[1];
        }
        uint32_t q[4];
        #pragma unroll
        for (int g = 0; g < 4; ++g) {
            uint32_t v = 0;
            #pragma unroll
            for (int j = 0; j < 4; ++j) {
                int qi = (int)rintf(p[4 * g + j] * qs);
                v |= ((uint32_t)qi & 0xffu) << (8 * j);
            }
            q[g] = v;
        }
        ws[i] = make_uint4(q[0], q[1], q[2], q[3]);
    } else if (i < nA + nO + nF) {
        int j = i - nA - nO;
        int o8 = j >> 9, s = j & 511;
        const float* p = &w_f[s * 256 + 8 * o8];
        ws[i] = make_uint4(pack_h2(p[0], p[1]), pack_h2(p[2], p[3]),
                           pack_h2(p[4], p[5]), pack_h2(p[6], p[7]));
    }
}

// ---------------------------------------------------------------------------
// Main sequential scan: one block per batch row, h state in registers (s=tid).
// A8i rows [0,NST) live in LDS (loaded once).  3 barriers per step.
// ---------------------------------------------------------------------------
__global__ __launch_bounds__(512)
void tncn_scan(const float* __restrict__ x,       // [512][128][256]
               const float* __restrict__ h_init,  // [128][512]
               const float* __restrict__ b_o,     // [256]
               const float* __restrict__ b_r,     // [512]
               const uint4* __restrict__ wsv,
               float* __restrict__ out)           // [512][128][256]
{
    const uint4* A8i = wsv;                       // [32][512]
    const uint4* O8i = wsv + 32 * 512;            // [32][256]
    const uint4* F4  = wsv + 32 * 512 + 32 * 256; // [32][512]
    const float* scv = (const float*)(wsv + 32 * 512 + 32 * 256 + 32 * 512);

    extern __shared__ __align__(16) char smem_raw[];
    uint4* sA = (uint4*)smem_raw;                 // [NST*512] staged A8i rows

    __shared__ __align__(16) signed char thA8[512];  // i8 tanh(h_post)
    __shared__ __align__(16) signed char thB8[512];  // i8 tanh(h_prior)
    __shared__ __align__(16) _Float16 erh[256];      // f16 error vector

    const int b   = blockIdx.x;
    const int tid = threadIdx.x;

    const float brf = b_r[tid];
    const float bof = (tid < 256) ? b_o[tid] : 0.0f;
    // Dequant factors: weight q*(max/127) times act q*(1/127).
    const float fA = scv[0] * (1.0f / 16129.0f);
    const float fO = scv[1] * (1.0f / 16129.0f);

    // Stage A8i rows [0, NST) into LDS once (coalesced).
    #pragma unroll
    for (int r = 0; r < NST; ++r)
        sA[r * 512 + tid] = A8i[r * 512 + tid];

    float hpost = h_init[b * SD + tid];
    thA8[tid] = (signed char)__float2int_rn(tanh_fast(hpost) * 127.0f);
    __syncthreads();

    const uint4* actA = (const uint4*)thA8;   // [32] x 16 acts
    const uint4* actB = (const uint4*)thB8;

    for (int t = 0; t < SEQ; ++t) {
        // Hoisted x_t load (consumed one matvec later; latency hidden).
        float xv = 0.0f;
        if (tid < 256) xv = x[(t * BATCH + b) * OD + tid];

        // ---- Phase A: h_prior[s=tid] = 0.5*h + 0.5*(tanh(h)@w_r^T + b_r)
        // Even/odd accumulator split (int adds: exact).
        int acc0 = 0, acc1 = 0;
        #pragma unroll
        for (int k16 = 0; k16 < NST; ++k16) {         // LDS-staged rows 0..6
            if (k16 & 1) acc1 = dot16i(sA[(k16 << 9) + tid], actA[k16], acc1);
            else         acc0 = dot16i(sA[(k16 << 9) + tid], actA[k16], acc0);
        }
        #pragma unroll 6
        for (int k16 = NST; k16 < 31; k16 += 2) {     // L2 stream pairs 7..30
            acc1 = dot16i(A8i[(k16 << 9) + tid],       actA[k16],     acc1);
            acc0 = dot16i(A8i[((k16 + 1) << 9) + tid], actA[k16 + 1], acc0);
        }
        acc1 = dot16i(A8i[(31 << 9) + tid], actA[31], acc1);
        float hp = 0.5f * hpost + 0.5f * ((float)(acc0 + acc1) * fA + brf);
        thB8[tid] = (signed char)__float2int_rn(tanh_fast(hp) * 127.0f);
        __syncthreads();

        // ---- Phase B: 256 threads, full k-range (same bytes, no part[]
        //      reduction barrier).  x_pred[o] = ... ; err = xp - x
        if (tid < 256) {
            int b0 = 0, b1 = 0;
            #pragma unroll 8
            for (int k16 = 0; k16 < 32; k16 += 2) {
                b0 = dot16i(O8i[(k16 << 8) + tid],       actB[k16],     b0);
                b1 = dot16i(O8i[((k16 + 1) << 8) + tid], actB[k16 + 1], b1);
            }
            float xp = (float)(b0 + b1) * fO + bof;
            float e  = xp - xv;
            erh[tid] = (_Float16)e;
            out[(t * BATCH + b) * OD + tid] = e;
        }
        __syncthreads();

        // ---- Phase C: h_post[s] = h_prior - 0.01*sign(h_prior) - 0.5*(er@w_f^T)
        float accC0 = 0.0f, accC1 = 0.0f;
        #pragma unroll 8
        for (int o8 = 0; o8 < 32; o8 += 2) {
            accC0 = dot8(F4[(o8 << 9) + tid],
                         *(const uint4*)&erh[8 * o8],       accC0);
            accC1 = dot8(F4[((o8 + 1) << 9) + tid],
                         *(const uint4*)&erh[8 * (o8 + 1)], accC1);
        }
        float accC = accC0 + accC1;
        float sg = (hp > 0.0f) ? 1.0f : ((hp < 0.0f) ? -1.0f : 0.0f);
        hpost = hp - 0.01f * sg - 0.5f * accC;
        thA8[tid] = (signed char)__float2int_rn(tanh_fast(hpost) * 127.0f);
        __syncthreads();
    }
}

extern "C" void kernel_launch(void* const* d_in, const int* in_sizes, int n_in,
                              void* d_out, int out_size, void* d_ws, size_t ws_size,
                              hipStream_t stream)
{
    // setup_inputs order: x, h_init, w_o, b_o, w_r, b_r, w_f, w_i
    const float* x  = (const float*)d_in[0];
    const float* h0 = (const float*)d_in[1];
    const float* wo = (const float*)d_in[2];
    const float* bo = (const float*)d_in[3];
    const float* wr = (const float*)d_in[4];
    const float* br = (const float*)d_in[5];
    const float* wf = (const float*)d_in[6];
    // d_in[7] (w_i) multiplies a zeros tensor in the reference — unused.

    uint4* ws  = (uint4*)d_ws;
    float* out = (float*)d_out;

    const int total_img = 32 * 512 + 32 * 256 + 32 * 512;  // 40960 uint4
    float* sc = (float*)(ws + total_img);

    compute_scales<<<2, 1024, 0, stream>>>(wr, wo, sc);
    pack_weights<<<(total_img + 255) / 256, 256, 0, stream>>>(wo, wr, wf, ws);
    tncn_scan<<<BATCH, 512, NST * 512 * 16, stream>>>(x, h0, bo, br, ws, out);
}

// Round 12
// 2764.982 us; speedup vs baseline: 1.3576x; 1.3576x over previous
//
#include <hip/hip_runtime.h>
#include <stdint.h>

// P_TNCN: seq=512, batch=128, states=512, out=256, inv_tau=0.5,
// alpha=0.01, beta=0.5.  float32 I/O.
//
// Per step (per batch row b, independent across b):
//   h_prior = 0.5*h + 0.5*(tanh(h) @ w_r^T + b_r)          [w_i term == 0]
//   x_pred  = tanh(h_prior) @ w_o^T + b_o
//   error   = x_pred - x_t                                   (output)
//   h_post  = h_prior - 0.01*sign(h_prior) - 0.5*(error @ w_f^T)
//
// R14: PURE REVERT to R11 (2775us, best verified).  R12 (w_f byte-cut) and
// R13 (phase-B 256-thread + accumulator split) both regressed 15-35% with
// the same signature: VALUBusy down, stall up - R11's exact phase/load-issue
// structure is the optimum found; structural edits around it are fragile in
// ways the cycle model doesn't capture.  No tweaks bundled with this revert.
// R11 recap: w_r/w_o per-matrix-scaled i8 via v_dot4_i32_i8 (sdot4, 4 MACs/
// inst, zero decode); acts quantized to i8 scale 127 (tanh range exact);
// w_f stays f16 via v_dot2_f32_f16 (sensitive O(1)-error path); 584 KB/step
// L2 weight stream; NST=7 rows of A staged in 56 KB dyn LDS; 128 blk x 512
// thr.  Workspace: 640 KB + 8 B.

#define SEQ   512
#define BATCH 128
#define SD    512
#define OD    256
#define NST   7     // A rows staged in LDS (7*512*16B = 57344 B)

typedef _Float16 h2_t __attribute__((ext_vector_type(2)));

#if __has_builtin(__builtin_amdgcn_fdot2)
#define HAS_FDOT2 1
#else
#define HAS_FDOT2 0
#endif
#if __has_builtin(__builtin_amdgcn_sdot4)
#define HAS_SDOT4 1
#else
#define HAS_SDOT4 0
#endif

__device__ __forceinline__ float tanh_fast(float x) {
    float e = __expf(2.0f * x);
    return 1.0f - 2.0f / (e + 1.0f);
}

__device__ __forceinline__ uint32_t pack_h2(float a, float b) {
    h2_t v;
    v.x = (_Float16)a;
    v.y = (_Float16)b;
    return __builtin_bit_cast(uint32_t, v);
}

__device__ __forceinline__ float dot2acc(uint32_t w, uint32_t a, float acc) {
#if HAS_FDOT2
    return __builtin_amdgcn_fdot2(__builtin_bit_cast(h2_t, a),
                                  __builtin_bit_cast(h2_t, w), acc, false);
#else
    h2_t av = __builtin_bit_cast(h2_t, a);
    h2_t wv = __builtin_bit_cast(h2_t, w);
    acc += (float)av.x * (float)wv.x;
    acc += (float)av.y * (float)wv.y;
    return acc;
#endif
}

// f16 path (phase C): uint4 = 8 f16 weights vs 8 f16 acts.
__device__ __forceinline__ float dot8(uint4 w, uint4 a, float acc) {
    acc = dot2acc(w.x, a.x, acc);
    acc = dot2acc(w.y, a.y, acc);
    acc = dot2acc(w.z, a.z, acc);
    acc = dot2acc(w.w, a.w, acc);
    return acc;
}

// i8 path: 4 signed-i8 MACs per instruction, i32 accumulate.
__device__ __forceinline__ int dot4i(uint32_t w, uint32_t a, int acc) {
#if HAS_SDOT4
    return __builtin_amdgcn_sdot4((int)w, (int)a, acc, false);
#else
    #pragma unroll
    for (int i = 0; i < 4; ++i)
        acc += (int)(signed char)((w >> (8 * i)) & 0xffu)
             * (int)(signed char)((a >> (8 * i)) & 0xffu);
    return acc;
#endif
}
// uint4 = 16 i8 weights vs 16 i8 acts.
__device__ __forceinline__ int dot16i(uint4 w, uint4 a, int acc) {
    acc = dot4i(w.x, a.x, acc);
    acc = dot4i(w.y, a.y, acc);
    acc = dot4i(w.z, a.z, acc);
    acc = dot4i(w.w, a.w, acc);
    return acc;
}

// ---------------------------------------------------------------------------
// Workspace layout (uint4 units):
//   A8i [32][512] : i8 w_r, A8i[k16][s] bytes = w_r[s][16k16..16k16+15] (256 KB)
//   O8i [32][256] : i8 w_o, O8i[k16][o] likewise                        (128 KB)
//   F4  [32][512] : f16 w_f, F4[o8][s] = w_f[s][8o8..8o8+7]             (256 KB)
//   scales: 2 floats at uint4-offset 40960: max|w_r|, max|w_o|.
// ---------------------------------------------------------------------------

__global__ void compute_scales(const float* __restrict__ w_r,
                               const float* __restrict__ w_o,
                               float* __restrict__ sc)
{
    __shared__ float red[1024];
    const float* src = (blockIdx.x == 0) ? w_r : w_o;
    const int n = (blockIdx.x == 0) ? (512 * 512) : (256 * 512);
    float m = 0.0f;
    for (int i = threadIdx.x; i < n; i += 1024) m = fmaxf(m, fabsf(src[i]));
    red[threadIdx.x] = m;
    __syncthreads();
    for (int off = 512; off > 0; off >>= 1) {
        if (threadIdx.x < off)
            red[threadIdx.x] = fmaxf(red[threadIdx.x], red[threadIdx.x + off]);
        __syncthreads();
    }
    if (threadIdx.x == 0) sc[blockIdx.x] = fmaxf(red[0], 1e-20f);
}

__global__ void pack_weights(const float* __restrict__ w_o,
                             const float* __restrict__ w_r,
                             const float* __restrict__ w_f,
                             uint4* __restrict__ ws)
{
    const int nA = 32 * 512;   // 16384 uint4
    const int nO = 32 * 256;   //  8192
    const int nF = 32 * 512;   // 16384
    const float* sc = (const float*)(ws + nA + nO + nF);
    int i = blockIdx.x * 256 + threadIdx.x;
    if (i < nA + nO) {
        const float* p;
        float qs;
        if (i < nA) {
            int k16 = i >> 9, s = i & 511;
            p  = &w_r[s * 512 + 16 * k16];
            qs = 127.0f / sc[0];
        } else {
            int j = i - nA;
            int k16 = j >> 8, o = j & 255;
            p  = &w_o[o * 512 + 16 * k16];
            qs = 127.0f / sc[1];
        }
        uint32_t q[4];
        #pragma unroll
        for (int g = 0; g < 4; ++g) {
            uint32_t v = 0;
            #pragma unroll
            for (int j = 0; j < 4; ++j) {
                int qi = (int)rintf(p[4 * g + j] * qs);
                v |= ((uint32_t)qi & 0xffu) << (8 * j);
            }
            q[g] = v;
        }
        ws[i] = make_uint4(q[0], q[1], q[2], q[3]);
    } else if (i < nA + nO + nF) {
        int j = i - nA - nO;
        int o8 = j >> 9, s = j & 511;
        const float* p = &w_f[s * 256 + 8 * o8];
        ws[i] = make_uint4(pack_h2(p[0], p[1]), pack_h2(p[2], p[3]),
                           pack_h2(p[4], p[5]), pack_h2(p[6], p[7]));
    }
}

// ---------------------------------------------------------------------------
// Main sequential scan: one block per batch row, h state in registers (s=tid).
// A8i rows [0,NST) live in LDS (loaded once); ascending-k accumulation.
// ---------------------------------------------------------------------------
__global__ __launch_bounds__(512)
void tncn_scan(const float* __restrict__ x,       // [512][128][256]
               const float* __restrict__ h_init,  // [128][512]
               const float* __restrict__ b_o,     // [256]
               const float* __restrict__ b_r,     // [512]
               const uint4* __restrict__ wsv,
               float* __restrict__ out)           // [512][128][256]
{
    const uint4* A8i = wsv;                       // [32][512]
    const uint4* O8i = wsv + 32 * 512;            // [32][256]
    const uint4* F4  = wsv + 32 * 512 + 32 * 256; // [32][512]
    const float* scv = (const float*)(wsv + 32 * 512 + 32 * 256 + 32 * 512);

    extern __shared__ __align__(16) char smem_raw[];
    uint4* sA = (uint4*)smem_raw;                 // [NST*512] staged A8i rows

    __shared__ __align__(16) signed char thA8[512];  // i8 tanh(h_post)
    __shared__ __align__(16) signed char thB8[512];  // i8 tanh(h_prior)
    __shared__ __align__(16) _Float16 erh[256];      // f16 error vector
    __shared__ float part[512];                      // x_pred partial sums

    const int b   = blockIdx.x;
    const int tid = threadIdx.x;
    const int o   = tid & 255;
    const int kh  = tid >> 8;    // 0/1: k-half for phase B

    const float brf = b_r[tid];
    const float bof = (tid < 256) ? b_o[tid] : 0.0f;
    // Dequant factors: weight q*(max/127) times act q*(1/127).
    const float fA = scv[0] * (1.0f / 16129.0f);
    const float fO = scv[1] * (1.0f / 16129.0f);

    // Stage A8i rows [0, NST) into LDS once (coalesced).
    #pragma unroll
    for (int r = 0; r < NST; ++r)
        sA[r * 512 + tid] = A8i[r * 512 + tid];

    float hpost = h_init[b * SD + tid];
    thA8[tid] = (signed char)__float2int_rn(tanh_fast(hpost) * 127.0f);
    __syncthreads();

    const uint4* actA = (const uint4*)thA8;   // [32] x 16 acts
    const uint4* actB = (const uint4*)thB8;

    for (int t = 0; t < SEQ; ++t) {
        // Hoisted x_t load (consumed one matvec later; latency hidden).
        float xv = 0.0f;
        if (tid < 256) xv = x[(t * BATCH + b) * OD + tid];

        // ---- Phase A: h_prior[s=tid] = 0.5*h + 0.5*(tanh(h)@w_r^T + b_r)
        int acci = 0;
        #pragma unroll
        for (int k16 = 0; k16 < NST; ++k16)            // LDS-staged rows
            acci = dot16i(sA[(k16 << 9) + tid], actA[k16], acci);
        #pragma unroll 5
        for (int k16 = NST; k16 < 32; ++k16)           // L2 stream
            acci = dot16i(A8i[(k16 << 9) + tid], actA[k16], acci);
        float hp = 0.5f * hpost + 0.5f * ((float)acci * fA + brf);
        thB8[tid] = (signed char)__float2int_rn(tanh_fast(hp) * 127.0f);
        __syncthreads();

        // ---- Phase B: x_pred[o] = tanh(h_prior)@w_o^T + b_o ; err = xp - x
        int accBi = 0;
        {
            const int k160 = kh * 16;
            #pragma unroll 8
            for (int k16i = 0; k16i < 16; ++k16i) {
                const int k16 = k160 + k16i;
                accBi = dot16i(O8i[(k16 << 8) + o], actB[k16], accBi);
            }
        }
        part[tid] = (float)accBi * fO;
        __syncthreads();
        if (tid < 256) {
            float xp = part[tid] + part[tid + 256] + bof;
            float e  = xp - xv;
            erh[tid] = (_Float16)e;
            out[(t * BATCH + b) * OD + tid] = e;
        }
        __syncthreads();

        // ---- Phase C: h_post[s] = h_prior - 0.01*sign(h_prior) - 0.5*(er@w_f^T)
        float accC = 0.0f;
        #pragma unroll 8
        for (int o8 = 0; o8 < 32; ++o8) {
            uint4 u = F4[(o8 << 9) + tid];
            uint4 e = *(const uint4*)&erh[8 * o8];
            accC = dot8(u, e, accC);
        }
        float sg = (hp > 0.0f) ? 1.0f : ((hp < 0.0f) ? -1.0f : 0.0f);
        hpost = hp - 0.01f * sg - 0.5f * accC;
        thA8[tid] = (signed char)__float2int_rn(tanh_fast(hpost) * 127.0f);
        __syncthreads();
    }
}

extern "C" void kernel_launch(void* const* d_in, const int* in_sizes, int n_in,
                              void* d_out, int out_size, void* d_ws, size_t ws_size,
                              hipStream_t stream)
{
    // setup_inputs order: x, h_init, w_o, b_o, w_r, b_r, w_f, w_i
    const float* x  = (const float*)d_in[0];
    const float* h0 = (const float*)d_in[1];
    const float* wo = (const float*)d_in[2];
    const float* bo = (const float*)d_in[3];
    const float* wr = (const float*)d_in[4];
    const float* br = (const float*)d_in[5];
    const float* wf = (const float*)d_in[6];
    // d_in[7] (w_i) multiplies a zeros tensor in the reference — unused.

    uint4* ws  = (uint4*)d_ws;
    float* out = (float*)d_out;

    const int total_img = 32 * 512 + 32 * 256 + 32 * 512;  // 40960 uint4
    float* sc = (float*)(ws + total_img);

    compute_scales<<<2, 1024, 0, stream>>>(wr, wo, sc);
    pack_weights<<<(total_img + 255) / 256, 256, 0, stream>>>(wo, wr, wf, ws);
    tncn_scan<<<BATCH, 512, NST * 512 * 16, stream>>>(x, h0, bo, br, ws, out);
}